// Round 13
// baseline (9278.004 us; speedup 1.0000x reference)
//
#include <hip/hip_runtime.h>
#include <hip/hip_cooperative_groups.h>
#include <math.h>

namespace cg = cooperative_groups;

#define B    32
#define H    1024
#define EMB  512
#define V    32000
#define SOS  1
#define NBLK 256
#define NTHR 1024

// ws float offsets
#define OFF_X   0            // EMB*B
#define OFF_HA  16384        // H*B
#define OFF_HB  49152        // H*B
#define OFF_P   81920        // float4[250][32] = 32000 floats
#define OFF_C   113920       // T*B
#define OFF_HHI 115968       // short[H*B] (16384 floats)
#define OFF_HLO 132352       // short[H*B]
#define OFF_WHI 148736       // short[V*H] (16384000 floats)
#define OFF_WLO 16532736     // short[V*H]

#define NEG_INF (-3.0e38f)

typedef float f4v   __attribute__((ext_vector_type(4)));
typedef short short8v __attribute__((ext_vector_type(8)));
typedef float f32x4 __attribute__((ext_vector_type(4)));

#define MF(a,b,c) c = __builtin_amdgcn_mfma_f32_16x16x32_bf16(a, b, c, 0, 0, 0)

__device__ __forceinline__ unsigned short rnb(float x) {
    unsigned u = __float_as_uint(x);
    unsigned r = u + 0x7FFFu + ((u >> 16) & 1u);
    return (unsigned short)(r >> 16);
}
__device__ __forceinline__ float bfh(unsigned short s) {
    return __uint_as_float(((unsigned)s) << 16);
}
__device__ __forceinline__ void sm_merge(float& m, float& l, int& a,
                                         float om, float ol, int oa)
{
    const bool take = (om > m) || (om == m && oa < a);
    const float mn = take ? om : m;
    const int   an = take ? oa : a;
    l = l * expf(m - mn) + ol * expf(om - mn);
    m = mn; a = an;
}

// smem carve (floats): proj Red[2][128][33]=8448 | Dt[32][132]=4224 | bl 128 | pm 128 | pls 128 | pa 128
__global__ __launch_bounds__(NTHR, 4) void k_all(
    const float* __restrict__ ih, const float* __restrict__ emb,
    const float* __restrict__ wih, const float* __restrict__ bih,
    const float* __restrict__ whh, const float* __restrict__ bhh,
    const float* __restrict__ wout, const float* __restrict__ bout,
    float* __restrict__ out, float* __restrict__ ws, int T)
{
    cg::grid_group grid = cg::this_grid();
    __shared__ __align__(16) float smem[13184];   // 52.7 KB
    __shared__ int stok_s;

    const int t   = threadIdx.x;
    const int blk = blockIdx.x;
    const size_t gid = (size_t)blk * NTHR + t;

    float*  xG  = ws + OFF_X;
    float*  hA  = ws + OFF_HA;
    float*  hB  = ws + OFF_HB;
    float4* P   = (float4*)(ws + OFF_P);
    float*  C   = ws + OFF_C;
    short*  Hhi = (short*)(ws + OFF_HHI);
    short*  Hlo = (short*)(ws + OFF_HLO);
    short*  Whi = (short*)(ws + OFF_WHI);
    short*  Wlo = (short*)(ws + OFF_WLO);

    // ================= INIT =================
    for (size_t i = gid; i < EMB * B; i += (size_t)NBLK * NTHR)
        xG[i] = tanhf(emb[(size_t)SOS * EMB + (i >> 5)]);
    for (size_t i = gid; i < H * B; i += (size_t)NBLK * NTHR) {
        int j = (int)(i >> 5), b = (int)(i & 31);
        hA[j * 32 + b] = ih[(size_t)b * H + j];
    }
    for (size_t i = gid; i < (size_t)V * H; i += (size_t)NBLK * NTHR) {
        const float x = wout[i];
        const unsigned short hi = rnb(x);
        Whi[i] = (short)hi;
        Wlo[i] = (short)rnb(x - bfh(hi));
    }
    grid.sync();

    for (int st = 0; st < T; ++st) {
        float* hold = (st & 1) ? hB : hA;
        float* hnew = (st & 1) ? hA : hB;
        float* orow = out + (size_t)st * B * V;

        // ================= GRU (R12 body) =================
        {
            float* sred = smem;               // [4][1152]
            const int ks = t >> 7;
            const int pl = t & 127;
            const int p  = blk * 128 + pl;
            const int b  = p & 31;
            const int j  = p >> 5;

            float ar = 0.f, az = 0.f, ain = 0.f, ahn = 0.f;
            const int k0 = ks * 192, k1 = k0 + 192;

            const int xe = (k1 < EMB) ? k1 : EMB;
            for (int k = k0; k < xe; k += 4) {
                const float u0 = xG[(k + 0) * 32 + b];
                const float u1 = xG[(k + 1) * 32 + b];
                const float u2 = xG[(k + 2) * 32 + b];
                const float u3 = xG[(k + 3) * 32 + b];
                const float4 w0 = *(const float4*)&wih[(size_t)(0 * H + j) * EMB + k];
                const float4 w1 = *(const float4*)&wih[(size_t)(1 * H + j) * EMB + k];
                const float4 w2 = *(const float4*)&wih[(size_t)(2 * H + j) * EMB + k];
                ar  = fmaf(w0.x, u0, fmaf(w0.y, u1, fmaf(w0.z, u2, fmaf(w0.w, u3, ar))));
                az  = fmaf(w1.x, u0, fmaf(w1.y, u1, fmaf(w1.z, u2, fmaf(w1.w, u3, az))));
                ain = fmaf(w2.x, u0, fmaf(w2.y, u1, fmaf(w2.z, u2, fmaf(w2.w, u3, ain))));
            }
            const int hs = (k0 > EMB) ? k0 : EMB;
            for (int k = hs; k < k1; k += 4) {
                const int kh = k - EMB;
                const float u0 = hold[(kh + 0) * 32 + b];
                const float u1 = hold[(kh + 1) * 32 + b];
                const float u2 = hold[(kh + 2) * 32 + b];
                const float u3 = hold[(kh + 3) * 32 + b];
                const float4 w0 = *(const float4*)&whh[(size_t)(0 * H + j) * H + kh];
                const float4 w1 = *(const float4*)&whh[(size_t)(1 * H + j) * H + kh];
                const float4 w2 = *(const float4*)&whh[(size_t)(2 * H + j) * H + kh];
                ar  = fmaf(w0.x, u0, fmaf(w0.y, u1, fmaf(w0.z, u2, fmaf(w0.w, u3, ar))));
                az  = fmaf(w1.x, u0, fmaf(w1.y, u1, fmaf(w1.z, u2, fmaf(w1.w, u3, az))));
                ahn = fmaf(w2.x, u0, fmaf(w2.y, u1, fmaf(w2.z, u2, fmaf(w2.w, u3, ahn))));
            }

            sred[0 * 1152 + pl * 9 + ks] = ar;
            sred[1 * 1152 + pl * 9 + ks] = az;
            sred[2 * 1152 + pl * 9 + ks] = ain;
            sred[3 * 1152 + pl * 9 + ks] = ahn;
            __syncthreads();

            if (t < 128) {
                const int pp = blk * 128 + t;
                const int bb = pp & 31, jj = pp >> 5;
                float s0 = 0.f, s1 = 0.f, s2 = 0.f, s3 = 0.f;
#pragma unroll
                for (int q = 0; q < 8; ++q) {
                    s0 += sred[0 * 1152 + t * 9 + q];
                    s1 += sred[1 * 1152 + t * 9 + q];
                    s2 += sred[2 * 1152 + t * 9 + q];
                    s3 += sred[3 * 1152 + t * 9 + q];
                }
                float gr  = s0 + bih[jj]         + bhh[jj];
                float gz  = s1 + bih[H + jj]     + bhh[H + jj];
                float gin = s2 + bih[2 * H + jj];
                float ghn = s3 + bhh[2 * H + jj];
                float r = 1.f / (1.f + expf(-gr));
                float z = 1.f / (1.f + expf(-gz));
                float n = tanhf(gin + r * ghn);   // r multiplies hh-part only
                const int hidx = jj * 32 + bb;
                const float hv = (1.f - z) * n + z * hold[hidx];
                hnew[hidx] = hv;
                const unsigned short hi = rnb(hv);
                const unsigned short lo = rnb(hv - bfh(hi));
                const int pidx = (((jj >> 3) * 32) + bb) * 8 + (jj & 7);
                Hhi[pidx] = (short)hi;
                Hlo[pidx] = (short)lo;
            }
        }
        grid.sync();

        // ================= PROJ (250 tiles x 128 rows; 16 waves = 4 mh x 4 kq) =================
        if (blk < 250) {
            float* Red = smem;              // [2][128][33]
            float* Dt  = smem + 8448;       // [32][132]
            float* bl  = smem + 12672;      // [128]
            float* pm  = smem + 12800;      // [4][32]
            float* pls = smem + 12928;      // [4][32]
            int*   pa  = (int*)(smem + 13056);

            const int r0 = blk * 128;
            const int w  = t >> 6;
            const int mh = w >> 2;          // row group (32 rows)
            const int kq = w & 3;           // k parity mod 4
            const int l  = t & 63;
            const int lr = l & 15;
            const int lg = l >> 4;

            if (t < 128) bl[t] = bout[r0 + t];

            const short* pAh = Whi + (size_t)(r0 + mh * 32 + lr) * H + lg * 8;
            const short* pAl = Wlo + (size_t)(r0 + mh * 32 + lr) * H + lg * 8;
            const short* pBh = Hhi + ((size_t)lg * 32 + lr) * 8;
            const short* pBl = Hlo + ((size_t)lg * 32 + lr) * 8;

            f32x4 acc00 = {0.f, 0.f, 0.f, 0.f};
            f32x4 acc01 = {0.f, 0.f, 0.f, 0.f};
            f32x4 acc10 = {0.f, 0.f, 0.f, 0.f};
            f32x4 acc11 = {0.f, 0.f, 0.f, 0.f};

#pragma unroll 2
            for (int i = 0; i < 8; ++i) {
                const int c = 4 * i + kq;
                const short8v a0h = *(const short8v*)(pAh + c * 32);
                const short8v a0l = *(const short8v*)(pAl + c * 32);
                const short8v a1h = *(const short8v*)(pAh + 16 * H + c * 32);
                const short8v a1l = *(const short8v*)(pAl + 16 * H + c * 32);
                const short8v b0h = *(const short8v*)(pBh + c * 1024);
                const short8v b0l = *(const short8v*)(pBl + c * 1024);
                const short8v b1h = *(const short8v*)(pBh + c * 1024 + 128);
                const short8v b1l = *(const short8v*)(pBl + c * 1024 + 128);
                MF(a0h, b0h, acc00); MF(a0h, b0l, acc00); MF(a0l, b0h, acc00);
                MF(a0h, b1h, acc01); MF(a0h, b1l, acc01); MF(a0l, b1h, acc01);
                MF(a1h, b0h, acc10); MF(a1h, b0l, acc10); MF(a1l, b0h, acc10);
                MF(a1h, b1h, acc11); MF(a1h, b1l, acc11); MF(a1l, b1h, acc11);
            }

            // cross-kq reduce: (0,2) and (1,3), then (0,1)
            if (kq >= 2) {
                float* rp = Red + (kq - 2) * 4224;
#pragma unroll
                for (int mt = 0; mt < 2; ++mt)
#pragma unroll
                    for (int r = 0; r < 4; ++r) {
                        const int row = mh * 32 + mt * 16 + lg * 4 + r;
                        rp[row * 33 + lr]      = mt ? acc10[r] : acc00[r];
                        rp[row * 33 + 16 + lr] = mt ? acc11[r] : acc01[r];
                    }
            }
            __syncthreads();
            if (kq < 2) {
                const float* rp = Red + kq * 4224;
#pragma unroll
                for (int mt = 0; mt < 2; ++mt)
#pragma unroll
                    for (int r = 0; r < 4; ++r) {
                        const int row = mh * 32 + mt * 16 + lg * 4 + r;
                        const float e0 = rp[row * 33 + lr];
                        const float e1 = rp[row * 33 + 16 + lr];
                        if (mt) { acc10[r] += e0; acc11[r] += e1; }
                        else    { acc00[r] += e0; acc01[r] += e1; }
                    }
            }
            __syncthreads();
            if (kq == 1) {
                float* rp = Red;
#pragma unroll
                for (int mt = 0; mt < 2; ++mt)
#pragma unroll
                    for (int r = 0; r < 4; ++r) {
                        const int row = mh * 32 + mt * 16 + lg * 4 + r;
                        rp[row * 33 + lr]      = mt ? acc10[r] : acc00[r];
                        rp[row * 33 + 16 + lr] = mt ? acc11[r] : acc01[r];
                    }
            }
            __syncthreads();
            if (kq == 0) {
                const float* rp = Red;
                float val[2][2][4];
#pragma unroll
                for (int mt = 0; mt < 2; ++mt)
#pragma unroll
                    for (int r = 0; r < 4; ++r) {
                        const int row = mh * 32 + mt * 16 + lg * 4 + r;
                        const float bo = bl[row];
                        val[mt][0][r] = (mt ? acc10[r] : acc00[r]) + rp[row * 33 + lr] + bo;
                        val[mt][1][r] = (mt ? acc11[r] : acc01[r]) + rp[row * 33 + 16 + lr] + bo;
                    }
#pragma unroll
                for (int mt = 0; mt < 2; ++mt)
#pragma unroll
                    for (int nt = 0; nt < 2; ++nt)
#pragma unroll
                        for (int r = 0; r < 4; ++r)
                            Dt[(nt * 16 + lr) * 132 + mh * 32 + mt * 16 + lg * 4 + r] = val[mt][nt][r];

#pragma unroll
                for (int nt = 0; nt < 2; ++nt) {
                    float m = val[0][nt][0], ls = 1.f;
                    int a = r0 + mh * 32 + lg * 4;
#pragma unroll
                    for (int q = 1; q < 8; ++q) {
                        const int mt = q >> 2, r = q & 3;
                        const float x = val[mt][nt][r];
                        const int row = r0 + mh * 32 + mt * 16 + lg * 4 + r;
                        if (x > m) { ls = ls * expf(m - x) + 1.f; m = x; a = row; }
                        else       { ls += expf(x - m); }
                    }
                    sm_merge(m, ls, a, __shfl_xor(m, 16), __shfl_xor(ls, 16), __shfl_xor(a, 16));
                    sm_merge(m, ls, a, __shfl_xor(m, 32), __shfl_xor(ls, 32), __shfl_xor(a, 32));
                    if (lg == 0) { pm[mh * 32 + nt * 16 + lr] = m; pls[mh * 32 + nt * 16 + lr] = ls; pa[mh * 32 + nt * 16 + lr] = a; }
                }
            }
            __syncthreads();

            if (t < 32) {
                float m = pm[t], ls = pls[t]; int a = pa[t];
#pragma unroll
                for (int q = 1; q < 4; ++q) sm_merge(m, ls, a, pm[q * 32 + t], pls[q * 32 + t], pa[q * 32 + t]);
                P[blk * 32 + t] = make_float4(m, ls, (float)a, 0.f);
            }
            __syncthreads();

            // coalesced nt-stores: (b = t>>5, rq = t&31)
            const int sb = t >> 5, rq = t & 31;
            const f4v v = *(const f4v*)&Dt[sb * 132 + rq * 4];
            __builtin_nontemporal_store(v, (f4v*)&orow[(size_t)sb * V + r0 + rq * 4]);
        }
        grid.sync();

        // ================= FIN2 (blocks 0..31) =================
        if (blk < B) {
            const int b = blk;
            float* fm = smem;              // [512]
            float* fl = smem + 512;
            int*   fa = (int*)(smem + 1024);

            if (t < 512) {
                float m = NEG_INF, lsum = 0.f; int a = 0x7FFFFFFF;
                if (t < 250) {
                    const float4 p = P[t * 32 + b];
                    m = p.x; lsum = p.y; a = (int)p.z;
                }
                fm[t] = m; fl[t] = lsum; fa[t] = a;
            }
            __syncthreads();
            for (int s = 256; s > 0; s >>= 1) {
                if (t < s) {
                    float mm = fm[t]; float ll = fl[t]; int aa = fa[t];
                    sm_merge(mm, ll, aa, fm[t + s], fl[t + s], fa[t + s]);
                    fm[t] = mm; fl[t] = ll; fa[t] = aa;
                }
                __syncthreads();
            }
            if (t == 0) {
                C[st * 32 + b] = fm[0] + logf(fl[0]);
                stok_s = fa[0];
            }
            __syncthreads();
            const int TOK = stok_s;
            if (t < EMB)
                xG[t * 32 + b] = tanhf(emb[(size_t)TOK * EMB + t]);
        }
        grid.sync();
    }

    // ================= deferred log-softmax subtract =================
    for (int r = blk; r < T * B; r += NBLK) {
        const float c = C[r];
        f4v* row = (f4v*)(out + (size_t)r * V);
        for (int v = t; v < V / 4; v += NTHR) {
            f4v x = __builtin_nontemporal_load(&row[v]);
            x -= c;
            __builtin_nontemporal_store(x, &row[v]);
        }
    }
}

extern "C" void kernel_launch(void* const* d_in, const int* in_sizes, int n_in,
                              void* d_out, int out_size, void* d_ws, size_t ws_size,
                              hipStream_t stream)
{
    const float* p_ih   = (const float*)d_in[0];
    // d_in[1] encoder_outputs unused; d_in[2] tgt_len recovered from out_size
    const float* p_emb  = (const float*)d_in[3];
    const float* p_wih  = (const float*)d_in[4];
    const float* p_bih  = (const float*)d_in[5];
    const float* p_whh  = (const float*)d_in[6];
    const float* p_bhh  = (const float*)d_in[7];
    const float* p_wout = (const float*)d_in[8];
    const float* p_bout = (const float*)d_in[9];
    float* p_out = (float*)d_out;
    float* p_ws  = (float*)d_ws;
    int T = out_size / (B * V);

    void* args[] = { &p_ih, &p_emb, &p_wih, &p_bih, &p_whh, &p_bhh,
                     &p_wout, &p_bout, &p_out, &p_ws, &T };
    hipLaunchCooperativeKernel((void*)k_all, dim3(NBLK), dim3(NTHR), args, 0, stream);
}

// Round 15
// 3733.292 us; speedup vs baseline: 2.4852x; 2.4852x over previous
//
#include <hip/hip_runtime.h>
#include <math.h>

#define B    32
#define H    1024
#define EMB  512
#define V    32000
#define SOS  1

// ws float offsets (R12 layout)
#define OFF_X   0            // EMB*B
#define OFF_HA  16384        // H*B
#define OFF_HB  49152        // H*B
#define OFF_P   81920        // float4[500][32] = 64000 floats
#define OFF_C   145920       // T*B
#define OFF_HHI 147968       // short[H*B] (16384 floats)
#define OFF_HLO 164352       // short[H*B]
#define OFF_WHI 180736       // short[V*H] (16384000 floats)
#define OFF_WLO 16564736     // short[V*H]

#define NEG_INF (-3.0e38f)

typedef float f4v   __attribute__((ext_vector_type(4)));
typedef short short8v __attribute__((ext_vector_type(8)));
typedef float f32x4 __attribute__((ext_vector_type(4)));

#define MF(a,b,c) c = __builtin_amdgcn_mfma_f32_16x16x32_bf16(a, b, c, 0, 0, 0)

__device__ __forceinline__ unsigned short rnb(float x) {
    unsigned u = __float_as_uint(x);
    unsigned r = u + 0x7FFFu + ((u >> 16) & 1u);
    return (unsigned short)(r >> 16);
}
__device__ __forceinline__ float bfh(unsigned short s) {
    return __uint_as_float(((unsigned)s) << 16);
}
__device__ __forceinline__ void sm_merge(float& m, float& l, int& a,
                                         float om, float ol, int oa)
{
    const bool take = (om > m) || (om == m && oa < a);
    const float mn = take ? om : m;
    const int   an = take ? oa : a;
    l = l * expf(m - mn) + ol * expf(om - mn);
    m = mn; a = an;
}

// ---------------------------------------------------------------- INIT (+ W hi/lo split)
__global__ void k_init(const float* __restrict__ ih, const float* __restrict__ emb,
                       const float* __restrict__ wout, float* __restrict__ ws)
{
    const size_t idx = (size_t)blockIdx.x * blockDim.x + threadIdx.x;
    const size_t stride = (size_t)gridDim.x * blockDim.x;
    for (size_t i = idx; i < EMB * B; i += stride)
        ws[OFF_X + i] = tanhf(emb[(size_t)SOS * EMB + (i >> 5)]);
    for (size_t i = idx; i < H * B; i += stride) {
        int j = (int)(i >> 5), b = (int)(i & 31);
        ws[OFF_HA + j * 32 + b] = ih[(size_t)b * H + j];
    }
    short* Whi = (short*)(ws + OFF_WHI);
    short* Wlo = (short*)(ws + OFF_WLO);
    for (size_t i = idx; i < (size_t)V * H; i += stride) {
        const float x = wout[i];
        const unsigned short hi = rnb(x);
        Whi[i] = (short)hi;
        Wlo[i] = (short)rnb(x - bfh(hi));
    }
}

// ---------------------------------------------------------------- GRU (R12 body + h hi/lo pack)
__global__ __launch_bounds__(1024) void k_gru(
    const float* __restrict__ xG, const float* __restrict__ hold,
    const float* __restrict__ wih, const float* __restrict__ bih,
    const float* __restrict__ whh, const float* __restrict__ bhh,
    float* __restrict__ hnew, short* __restrict__ Hhi, short* __restrict__ Hlo)
{
    const int t   = threadIdx.x;
    const int blk = blockIdx.x;
    __shared__ float sred[4 * 1152];

    const int ks = t >> 7;
    const int pl = t & 127;
    const int p  = blk * 128 + pl;
    const int b  = p & 31;
    const int j  = p >> 5;

    float ar = 0.f, az = 0.f, ain = 0.f, ahn = 0.f;
    const int k0 = ks * 192, k1 = k0 + 192;

    const int xe = (k1 < EMB) ? k1 : EMB;
    for (int k = k0; k < xe; k += 4) {
        const float u0 = xG[(k + 0) * 32 + b];
        const float u1 = xG[(k + 1) * 32 + b];
        const float u2 = xG[(k + 2) * 32 + b];
        const float u3 = xG[(k + 3) * 32 + b];
        const float4 w0 = *(const float4*)&wih[(size_t)(0 * H + j) * EMB + k];
        const float4 w1 = *(const float4*)&wih[(size_t)(1 * H + j) * EMB + k];
        const float4 w2 = *(const float4*)&wih[(size_t)(2 * H + j) * EMB + k];
        ar  = fmaf(w0.x, u0, fmaf(w0.y, u1, fmaf(w0.z, u2, fmaf(w0.w, u3, ar))));
        az  = fmaf(w1.x, u0, fmaf(w1.y, u1, fmaf(w1.z, u2, fmaf(w1.w, u3, az))));
        ain = fmaf(w2.x, u0, fmaf(w2.y, u1, fmaf(w2.z, u2, fmaf(w2.w, u3, ain))));
    }
    const int hs = (k0 > EMB) ? k0 : EMB;
    for (int k = hs; k < k1; k += 4) {
        const int kh = k - EMB;
        const float u0 = hold[(kh + 0) * 32 + b];
        const float u1 = hold[(kh + 1) * 32 + b];
        const float u2 = hold[(kh + 2) * 32 + b];
        const float u3 = hold[(kh + 3) * 32 + b];
        const float4 w0 = *(const float4*)&whh[(size_t)(0 * H + j) * H + kh];
        const float4 w1 = *(const float4*)&whh[(size_t)(1 * H + j) * H + kh];
        const float4 w2 = *(const float4*)&whh[(size_t)(2 * H + j) * H + kh];
        ar  = fmaf(w0.x, u0, fmaf(w0.y, u1, fmaf(w0.z, u2, fmaf(w0.w, u3, ar))));
        az  = fmaf(w1.x, u0, fmaf(w1.y, u1, fmaf(w1.z, u2, fmaf(w1.w, u3, az))));
        ahn = fmaf(w2.x, u0, fmaf(w2.y, u1, fmaf(w2.z, u2, fmaf(w2.w, u3, ahn))));
    }

    sred[0 * 1152 + pl * 9 + ks] = ar;
    sred[1 * 1152 + pl * 9 + ks] = az;
    sred[2 * 1152 + pl * 9 + ks] = ain;
    sred[3 * 1152 + pl * 9 + ks] = ahn;
    __syncthreads();

    if (t < 128) {
        const int pp = blk * 128 + t;
        const int bb = pp & 31, jj = pp >> 5;
        float s0 = 0.f, s1 = 0.f, s2 = 0.f, s3 = 0.f;
#pragma unroll
        for (int q = 0; q < 8; ++q) {
            s0 += sred[0 * 1152 + t * 9 + q];
            s1 += sred[1 * 1152 + t * 9 + q];
            s2 += sred[2 * 1152 + t * 9 + q];
            s3 += sred[3 * 1152 + t * 9 + q];
        }
        float gr  = s0 + bih[jj]         + bhh[jj];
        float gz  = s1 + bih[H + jj]     + bhh[H + jj];
        float gin = s2 + bih[2 * H + jj];
        float ghn = s3 + bhh[2 * H + jj];
        float r = 1.f / (1.f + expf(-gr));
        float z = 1.f / (1.f + expf(-gz));
        float n = tanhf(gin + r * ghn);   // r multiplies hh-part only
        const int hidx = jj * 32 + bb;
        const float hv = (1.f - z) * n + z * hold[hidx];
        hnew[hidx] = hv;
        const unsigned short hi = rnb(hv);
        const unsigned short lo = rnb(hv - bfh(hi));
        const int pidx = (((jj >> 3) * 32) + bb) * 8 + (jj & 7);
        Hhi[pidx] = (short)hi;
        Hlo[pidx] = (short)lo;
    }
}

// ---------------------------------------------------------------- PROJ via bf16-MFMA (3-pass)
// 500 blocks x 512 thr (8 waves). Block: 64 rows x 32 b. Wave (mh = w>>2, kq = w&3):
// 2Mx2N tile (rows mh*32..+32) over k-chunks c = 4i+kq, i<8.
// Same grid-total load/MFMA counts as R12; 2x waves/SIMD for latency hiding.
__global__ __launch_bounds__(512, 4) void k_proj(
    const short* __restrict__ Whi, const short* __restrict__ Wlo,
    const short* __restrict__ Hhi, const short* __restrict__ Hlo,
    const float* __restrict__ bout, float* __restrict__ orow,
    float4* __restrict__ P)
{
    __shared__ float Red[4 * 32 * 33];      // [mh*2+par][row][b]  (4224 floats)
    __shared__ float Dt[32 * 68];           // [b][row+pad]
    __shared__ float bl[64];
    __shared__ float pm[2][32], pls[2][32];
    __shared__ int   pa[2][32];

    const int t   = threadIdx.x;
    const int blk = blockIdx.x;
    const int r0  = blk * 64;
    const int w   = t >> 6;
    const int mh  = w >> 2;                 // row half
    const int kq  = w & 3;                  // k parity (mod 4)
    const int l   = t & 63;
    const int lr  = l & 15;
    const int lg  = l >> 4;

    if (t < 64) bl[t] = bout[r0 + t];

    const short* pAh = Whi + (size_t)(r0 + mh * 32 + lr) * H + lg * 8;
    const short* pAl = Wlo + (size_t)(r0 + mh * 32 + lr) * H + lg * 8;
    const short* pBh = Hhi + ((size_t)lg * 32 + lr) * 8;
    const short* pBl = Hlo + ((size_t)lg * 32 + lr) * 8;

    f32x4 acc00 = {0.f, 0.f, 0.f, 0.f};
    f32x4 acc01 = {0.f, 0.f, 0.f, 0.f};
    f32x4 acc10 = {0.f, 0.f, 0.f, 0.f};
    f32x4 acc11 = {0.f, 0.f, 0.f, 0.f};

#pragma unroll 2
    for (int i = 0; i < 8; ++i) {
        const int c = 4 * i + kq;
        const short8v a0h = *(const short8v*)(pAh + c * 32);
        const short8v a0l = *(const short8v*)(pAl + c * 32);
        const short8v a1h = *(const short8v*)(pAh + 16 * H + c * 32);
        const short8v a1l = *(const short8v*)(pAl + 16 * H + c * 32);
        const short8v b0h = *(const short8v*)(pBh + c * 1024);
        const short8v b0l = *(const short8v*)(pBl + c * 1024);
        const short8v b1h = *(const short8v*)(pBh + c * 1024 + 128);
        const short8v b1l = *(const short8v*)(pBl + c * 1024 + 128);
        MF(a0h, b0h, acc00); MF(a0h, b0l, acc00); MF(a0l, b0h, acc00);
        MF(a0h, b1h, acc01); MF(a0h, b1l, acc01); MF(a0l, b1h, acc01);
        MF(a1h, b0h, acc10); MF(a1h, b0l, acc10); MF(a1l, b0h, acc10);
        MF(a1h, b1h, acc11); MF(a1h, b1l, acc11); MF(a1l, b1h, acc11);
    }

    // cross-kq reduce tree: (kq2,kq3) dump; (kq0,kq1) add; kq1 dump; kq0 add+finish
    if (kq >= 2) {
        float* rp = Red + (mh * 2 + (kq - 2)) * 1056;
#pragma unroll
        for (int mt = 0; mt < 2; ++mt)
#pragma unroll
            for (int r = 0; r < 4; ++r) {
                const int row = mt * 16 + lg * 4 + r;
                rp[row * 33 + lr]      = mt ? acc10[r] : acc00[r];
                rp[row * 33 + 16 + lr] = mt ? acc11[r] : acc01[r];
            }
    }
    __syncthreads();
    if (kq < 2) {
        const float* rp = Red + (mh * 2 + kq) * 1056;
#pragma unroll
        for (int mt = 0; mt < 2; ++mt)
#pragma unroll
            for (int r = 0; r < 4; ++r) {
                const int row = mt * 16 + lg * 4 + r;
                const float e0 = rp[row * 33 + lr];
                const float e1 = rp[row * 33 + 16 + lr];
                if (mt) { acc10[r] += e0; acc11[r] += e1; }
                else    { acc00[r] += e0; acc01[r] += e1; }
            }
    }
    __syncthreads();
    if (kq == 1) {
        float* rp = Red + mh * 2 * 1056;
#pragma unroll
        for (int mt = 0; mt < 2; ++mt)
#pragma unroll
            for (int r = 0; r < 4; ++r) {
                const int row = mt * 16 + lg * 4 + r;
                rp[row * 33 + lr]      = mt ? acc10[r] : acc00[r];
                rp[row * 33 + 16 + lr] = mt ? acc11[r] : acc01[r];
            }
    }
    __syncthreads();

    if (kq == 0) {
        const float* rp = Red + mh * 2 * 1056;
        float val[2][2][4];
#pragma unroll
        for (int mt = 0; mt < 2; ++mt)
#pragma unroll
            for (int r = 0; r < 4; ++r) {
                const int row = mt * 16 + lg * 4 + r;
                const float bo = bl[mh * 32 + row];
                val[mt][0][r] = (mt ? acc10[r] : acc00[r]) + rp[row * 33 + lr] + bo;
                val[mt][1][r] = (mt ? acc11[r] : acc01[r]) + rp[row * 33 + 16 + lr] + bo;
            }
#pragma unroll
        for (int mt = 0; mt < 2; ++mt)
#pragma unroll
            for (int nt = 0; nt < 2; ++nt)
#pragma unroll
                for (int r = 0; r < 4; ++r)
                    Dt[(nt * 16 + lr) * 68 + mh * 32 + mt * 16 + lg * 4 + r] = val[mt][nt][r];

#pragma unroll
        for (int nt = 0; nt < 2; ++nt) {
            float m = val[0][nt][0], ls = 1.f;
            int a = r0 + mh * 32 + lg * 4;
#pragma unroll
            for (int q = 1; q < 8; ++q) {
                const int mt = q >> 2, r = q & 3;
                const float x = val[mt][nt][r];
                const int row = r0 + mh * 32 + mt * 16 + lg * 4 + r;
                if (x > m) { ls = ls * expf(m - x) + 1.f; m = x; a = row; }
                else       { ls += expf(x - m); }
            }
            sm_merge(m, ls, a, __shfl_xor(m, 16), __shfl_xor(ls, 16), __shfl_xor(a, 16));
            sm_merge(m, ls, a, __shfl_xor(m, 32), __shfl_xor(ls, 32), __shfl_xor(a, 32));
            if (lg == 0) { pm[mh][nt * 16 + lr] = m; pls[mh][nt * 16 + lr] = ls; pa[mh][nt * 16 + lr] = a; }
        }
    }
    __syncthreads();

    if (t < 32) {
        float m = pm[0][t], ls = pls[0][t]; int a = pa[0][t];
        sm_merge(m, ls, a, pm[1][t], pls[1][t], pa[1][t]);
        P[blk * 32 + t] = make_float4(m, ls, (float)a, 0.f);
    }

    // coalesced nt-stores: thread (b = t>>4, rq = t&15) stores one f4v
    const int sb = t >> 4, rq = t & 15;
    const f4v v = *(const f4v*)&Dt[sb * 68 + rq * 4];
    __builtin_nontemporal_store(v, (f4v*)&orow[(size_t)sb * V + r0 + rq * 4]);
}

// ---------------------------------------------------------------- FIN2: 500 partials -> TOK, C, xG
__global__ __launch_bounds__(256) void k_fin2(
    const float4* __restrict__ partial, const float* __restrict__ emb,
    float* __restrict__ xG, float* __restrict__ C)
{
    const int b = blockIdx.x;
    const int t = threadIdx.x;
    __shared__ float fm[256], fl[256];
    __shared__ int   fa[256], stok;

    float m = NEG_INF, l = 0.f; int a = 0x7FFFFFFF;
    {
        float4 p = partial[t * 32 + b];
        m = p.x; l = p.y; a = (int)p.z;
    }
    if (t + 256 < 500) {
        float4 p = partial[(t + 256) * 32 + b];
        sm_merge(m, l, a, p.x, p.y, (int)p.z);
    }
    fm[t] = m; fl[t] = l; fa[t] = a;
    __syncthreads();
    for (int s = 128; s > 0; s >>= 1) {
        if (t < s) {
            const float om = fm[t + s], ol = fl[t + s];
            const int   oa = fa[t + s];
            float mm = fm[t]; float ll = fl[t]; int aa = fa[t];
            const bool take = (om > mm) || (om == mm && oa < aa);
            const float mn = take ? om : mm;
            const int   an = take ? oa : aa;
            ll = ll * expf(mm - mn) + ol * expf(om - mn);
            fm[t] = mn; fl[t] = ll; fa[t] = an;
        }
        __syncthreads();
    }
    if (t == 0) {
        C[b] = fm[0] + logf(fl[0]);
        stok = fa[0];
    }
    __syncthreads();
    const int TOK = stok;
    for (int k = t; k < EMB; k += 256)
        xG[k * 32 + b] = tanhf(emb[(size_t)TOK * EMB + k]);
}

// ---------------------------------------------------------------- deferred subtract
__global__ __launch_bounds__(256) void k_sub(float* __restrict__ out,
                                             const float* __restrict__ C)
{
    const int r = blockIdx.x;
    const float c = C[r];
    f4v* row = (f4v*)(out + (size_t)r * V);
    for (int v = threadIdx.x; v < V / 4; v += 256) {
        f4v x = __builtin_nontemporal_load(&row[v]);
        x -= c;
        __builtin_nontemporal_store(x, &row[v]);
    }
}

// ---------------------------------------------------------------- launch
extern "C" void kernel_launch(void* const* d_in, const int* in_sizes, int n_in,
                              void* d_out, int out_size, void* d_ws, size_t ws_size,
                              hipStream_t stream)
{
    const float* p_ih   = (const float*)d_in[0];
    // d_in[1] encoder_outputs unused; d_in[2] tgt_len recovered from out_size
    const float* p_emb  = (const float*)d_in[3];
    const float* p_wih  = (const float*)d_in[4];
    const float* p_bih  = (const float*)d_in[5];
    const float* p_whh  = (const float*)d_in[6];
    const float* p_bhh  = (const float*)d_in[7];
    const float* p_wout = (const float*)d_in[8];
    const float* p_bout = (const float*)d_in[9];
    float* out = (float*)d_out;
    float* ws  = (float*)d_ws;
    const int T = out_size / (B * V);

    float*  xG  = ws + OFF_X;
    float*  hA  = ws + OFF_HA;
    float*  hB  = ws + OFF_HB;
    float4* P   = (float4*)(ws + OFF_P);
    float*  C   = ws + OFF_C;
    short*  Hhi = (short*)(ws + OFF_HHI);
    short*  Hlo = (short*)(ws + OFF_HLO);
    short*  Whi = (short*)(ws + OFF_WHI);
    short*  Wlo = (short*)(ws + OFF_WLO);

    k_init<<<2048, 256, 0, stream>>>(p_ih, p_emb, p_wout, ws);

    for (int st = 0; st < T; ++st) {
        float* hold = (st & 1) ? hB : hA;
        float* hnew = (st & 1) ? hA : hB;
        float* orow = out + (size_t)st * B * V;
        k_gru<<<256, 1024, 0, stream>>>(xG, hold, p_wih, p_bih, p_whh, p_bhh,
                                        hnew, Hhi, Hlo);
        k_proj<<<500, 512, 0, stream>>>(Whi, Wlo, Hhi, Hlo, p_bout, orow, P);
        k_fin2<<<B, 256, 0, stream>>>(P, p_emb, xG, C + st * B);
    }
    k_sub<<<T * B, 256, 0, stream>>>(out, C);
}